// Round 12
// baseline (755.216 us; speedup 1.0000x reference)
//
#include <hip/hip_runtime.h>
#include <math.h>

#define N_IMG 16
#define CIN   64
#define CMID  128
#define CO    32
#define KHD   16
#define HL    128
#define WL    128
#define HO    256
#define WO    256
#define EPSV  1e-5f

typedef float f32x4 __attribute__((ext_vector_type(4)));
typedef _Float16 h8v __attribute__((ext_vector_type(8)));
typedef _Float16 h2v __attribute__((ext_vector_type(2)));

// ---------------- workspace layout (floats) ----------------
// [0, 33554432)            t (16,128,128,128)       -- dead after K3
// [33554432, 50331648)     refodd (16,16,256,256)   -- K5 overwrites in place with gx
// [50331648, +8192)        S1p (4,2048)
// [+8192, +8192)           S2p (4,2048)
// [+..., 65536 f32 slot)   wAf: f16 A-fragments (16 n x 4 cb x 2 mt x 64 lane x 8)
// [+..., 512)              beff (16,32)
// [+..., 8192)             w1T (64,128)  [c][o]
// gy lives in d_out (K6 stages its gy tile into LDS before overwriting).

// K0: transpose conv1 weights to [c][o] so K1 can read them wave-uniformly.
__global__ __launch_bounds__(256) void k0_transpose(const float* __restrict__ w1,
                                                    float* __restrict__ w1T) {
  int tid = threadIdx.x;
  for (int f = tid; f < CMID * CIN; f += 256) {
    int o = f >> 6, c = f & 63;
    w1T[c * CMID + o] = w1[f];
  }
}

// K1: t[n][o][y][x] = conv1_b[o] + sum_c conv1_w[o][c] * lo[n][c][y][x]
__global__ __launch_bounds__(512) void k1_conv1(const float* __restrict__ lo,
                                                const float* __restrict__ w1T,
                                                const float* __restrict__ b1,
                                                float* __restrict__ t) {
  int blk = blockIdx.x;        // n*128 + y
  int n = blk >> 7, y = blk & 127;
  __shared__ float lo_l[CIN * WL];    // [c][x]  32 KB
  int tid = threadIdx.x;
  const float* lo_base = lo + (size_t)n * CIN * (HL * WL) + y * WL;
  for (int f = tid; f < CIN * WL / 4; f += 512) {
    int c = f >> 5, xi = f & 31;
    ((float4*)lo_l)[f] = *(const float4*)(lo_base + (size_t)c * (HL * WL) + xi * 4);
  }
  __syncthreads();

  int wave = __builtin_amdgcn_readfirstlane(tid >> 6);  // force wave-uniform
  int lane = tid & 63;
  int half = wave >> 2;   // x-half
  int og   = wave & 3;    // 32-output group
  int x = half * 64 + lane;

  float acc[32];
#pragma unroll
  for (int o = 0; o < 32; ++o) acc[o] = 0.f;

  const float* wbase = w1T + og * 32;   // [c][o], stride CMID; uniform
  for (int c = 0; c < CIN; ++c) {
    float lv = lo_l[c * WL + x];
    const float* wr = wbase + c * CMID;
#pragma unroll
    for (int o = 0; o < 32; ++o) acc[o] += wr[o] * lv;
  }
  const float* bb = b1 + og * 32;       // uniform
  float* tb = t + ((size_t)n * CMID + og * 32) * (HL * WL) + y * WL + x;
#pragma unroll
  for (int o = 0; o < 32; ++o) tb[(size_t)o * (HL * WL)] = acc[o] + bb[o];
}

// Fast erf (A&S 7.1.26, |err| <= 1.5e-7), DIV-FREE: v_rcp instead of IEEE divide.
__device__ __forceinline__ float erf_fast(float x) {
  float ax = fabsf(x);
  float t = __builtin_amdgcn_rcpf(fmaf(0.3275911f, ax, 1.f));
  float e = __expf(-ax * ax);
  float poly = t * (0.254829592f +
              t * (-0.284496736f +
              t * (1.421413741f +
              t * (-1.453152027f +
              t * 1.061405429f))));
  float r = fmaf(-poly, e, 1.f);
  return copysignf(r, x);
}

__device__ __forceinline__ float gelu_fast(float v) {
  float h = 0.5f * v;
  return fmaf(h, erf_fast(v * 0.70710678118654752f), h);
}

// K2 (templated on Q): per (n,c): partial sum & sumsq of GELU(upsample(t[n,c]))
// over output rows [Q*64, Q*64+64). Entire y-schedule compile-time; rolling
// register pair of x-interped rows. (unchanged from round 10)
template <int Q>
__global__ __launch_bounds__(256) void k2_statsT(const float* __restrict__ t,
                                                 float* __restrict__ S1p,
                                                 float* __restrict__ S2p) {
  constexpr int I0  = Q * 64;
  constexpr int YLO = (I0 * 127) / 255;
  constexpr int YHI0 = ((I0 + 63) * 127) / 255 + 1;
  constexpr int YHI = (YHI0 > 127) ? 127 : YHI0;
  constexpr int NR  = YHI - YLO + 1;            // 33 or 34
  int nc = blockIdx.x;                          // 2048 blocks
  __shared__ float img[NR * WL];
  __shared__ float red[16];
  int tid = threadIdx.x;
  const float* tb = t + (size_t)nc * (HL * WL) + YLO * WL;
  for (int f = tid; f < NR * (WL / 4); f += 256)
    ((float4*)img)[f] = ((const float4*)tb)[f];
  __syncthreads();

  float xs = tid * (127.f / 255.f);
  float x0f = floorf(xs);
  int x0 = (int)x0f, x1 = min(x0 + 1, 127);
  float wx = xs - x0f, omwx = 1.f - wx;

  auto xv = [&](int r) {
    return img[r * WL + x0] * omwx + img[r * WL + x1] * wx;
  };

  float sum = 0.f, ssq = 0.f;
  float cur0 = xv(0);                  // row y0(I0) == YLO
  float cur1 = xv(1);                  // NR >= 2 always
#pragma unroll
  for (int k = 0; k < 64; ++k) {
    const int i = I0 + k;
    const int y0k = (i * 127) / 255;                 // compile-time
    if (k > 0 && y0k != ((i - 1) * 127) / 255) {     // static advance
      cur0 = cur1;
      if (y0k + 1 <= YHI) cur1 = xv(y0k + 1 - YLO);
    }
    const float wyk = (float)(i * 127 - 255 * y0k) * (1.f / 255.f);  // exact
    float v = (y0k + 1 <= YHI) ? fmaf(cur0, 1.f - wyk, cur1 * wyk)
                               : cur0;               // i==255: wy==0
    float g = gelu_fast(v);
    sum += g; ssq += g * g;
  }
  int lane = tid & 63, w = tid >> 6;
#pragma unroll
  for (int d = 32; d; d >>= 1) {
    sum += __shfl_xor(sum, d, 64);
    ssq += __shfl_xor(ssq, d, 64);
  }
  if (lane == 0) { red[w] = sum; red[8 + w] = ssq; }
  __syncthreads();
  if (tid == 0) {
    S1p[Q * 2048 + nc] = red[0] + red[1] + red[2] + red[3];
    S2p[Q * 2048 + nc] = red[8] + red[9] + red[10] + red[11];
  }
}

// K2b: fold GN + SE + conv2 into per-image effective weights + bias.
// Weights are emitted as f16 MFMA A-fragments for v_mfma_f32_16x16x32_f16:
//   A[row=o&15][k=c&31] of tile (cb=c>>5, mt=o>>4); lane = ((c&31)>>3)*16 + (o&15),
//   element j = c&7  ->  wAf[((n*4+cb)*2+mt)*512 + lane*8 + j]
__global__ __launch_bounds__(128) void k2b_prep(const float* __restrict__ S1p,
                                                const float* __restrict__ S2p,
                                                const float* __restrict__ gn_w,
                                                const float* __restrict__ gn_b,
                                                const float* __restrict__ se_w1,
                                                const float* __restrict__ se_w2,
                                                const float* __restrict__ w2,
                                                unsigned short* __restrict__ wAf,
                                                float* __restrict__ beff) {
  int n = blockIdx.x, c = threadIdx.x;
  int nc = n * 128 + c;
  __shared__ float mArr[128], eArr[128], pArr[128], hArr[16], dArr[128];
  const float inv = 1.f / 65536.f;
  float m  = (S1p[nc] + S1p[2048 + nc] + S1p[4096 + nc] + S1p[6144 + nc]) * inv;
  float e2 = (S2p[nc] + S2p[2048 + nc] + S2p[4096 + nc] + S2p[6144 + nc]) * inv;
  mArr[c] = m; eArr[c] = e2;
  __syncthreads();
  int g0 = (c >> 6) << 6;
  float mu = 0.f, E2 = 0.f;
  for (int q = 0; q < 64; ++q) { mu += mArr[g0 + q]; E2 += eArr[g0 + q]; }
  mu *= (1.f / 64.f); E2 *= (1.f / 64.f);
  float var = E2 - mu * mu;
  float rs = rsqrtf(var + EPSV);
  float gw = gn_w[c], gb = gn_b[c];
  pArr[c] = (m - mu) * rs * gw + gb;
  __syncthreads();
  if (c < 16) {
    float h = 0.f;
    for (int q = 0; q < 128; ++q) h += se_w1[c * 128 + q] * pArr[q];
    hArr[c] = fmaxf(h, 0.f);
  }
  __syncthreads();
  float sacc = 0.f;
  for (int q = 0; q < 16; ++q) sacc += se_w2[c * 16 + q] * hArr[q];
  float s = __builtin_amdgcn_rcpf(1.f + __expf(-sacc));
  float a = s * gw * rs;
  float d = s * (gb - gw * rs * mu);
  dArr[c] = d;
  __syncthreads();
  int cb = c >> 5;
  int lbase = ((c >> 3) & 3) << 4;   // (lane>>4) = (c&31)>>3
  int j = c & 7;
#pragma unroll
  for (int o = 0; o < 32; ++o) {
    int mt = o >> 4;
    size_t idx = ((size_t)n * 8 + (size_t)(cb * 2 + mt)) * 512 +
                 (size_t)((lbase + (o & 15)) * 8 + j);
    _Float16 hv = (_Float16)(w2[o * 128 + c] * a);
    wAf[idx] = __builtin_bit_cast(unsigned short, hv);
  }
  if (c < 32) {
    float bb = 0.f;
    for (int q = 0; q < 128; ++q) bb += w2[c * 128 + q] * dArr[q];
    beff[n * 32 + c] = bb;
  }
}

// K3 v2: TWO output rows per block (512 threads, grid 2048). Consecutive rows
// share their t source rows, so staging combines both rows' y-interp in ONE
// pass and the 4 barriers per cb now serve 2 rows (per-row barrier/staging
// cost halved -- round 11 showed k3 plateaued at ~150us, issue+barrier-bound).
// LDS = one 32.8 KB region shared by: staging [2][32][128] f32 | f16 B-panel
// (512 x 64B) | D-phase slots | epilogue lmax/lsum. 4 blocks/CU = 32 waves.
__global__ __launch_bounds__(512, 8) void k3_ref2(const float* __restrict__ t,
                                                  const unsigned short* __restrict__ wAf,
                                                  const float* __restrict__ beff,
                                                  float* __restrict__ refodd,
                                                  float* __restrict__ gy) {
  int blk = (blockIdx.x & 7) * 256 + (blockIdx.x >> 3);  // bijective: 2048 = 8*256
  int n = blk >> 7, p2 = blk & 127;
  int i0 = 2 * p2;                     // rows i0, i0+1
  __shared__ float smem[8196];         // 32,784 B: 8192 shared + 4 guard
  int tid = threadIdx.x;
  char* glb = (char*)smem;             // f16 B-panel view (512 rows x 64B)
  float* lmaxS = smem;                 // epilogue alias (behind barrier)
  float* lsumS = smem + 128;
  const float* bn = beff + n * CO;     // uniform

  if (tid < 4) smem[8192 + tid] = 0.f; // guard: finite for the x0+1 read at
                                       // cc=31,px=255 of half 1; half 0's
                                       // equivalent read lands in half 1's
                                       // staged data (finite, x-weight 0)

  int lane = tid & 63;
  h8v wfrag[8];                        // A-frags: [cb][mt], resident all kernel
#pragma unroll
  for (int u = 0; u < 8; ++u)
    wfrag[u] = *(const h8v*)(wAf + ((size_t)n * 8 + u) * 512 + lane * 8);

  // y-params for BOTH rows (used by staging); own-row params for gelu phase.
  float ysA = i0 * (127.f / 255.f);
  float y0fA = floorf(ysA);
  int y0A = (int)y0fA, y1A = min(y0A + 1, 127);
  float wyA = ysA - y0fA, omwyA = 1.f - wyA;
  float ysB = (i0 + 1) * (127.f / 255.f);
  float y0fB = floorf(ysB);
  int y0B = (int)y0fB, y1B = min(y0B + 1, 127);
  float wyB = ysB - y0fB, omwyB = 1.f - wyB;

  int half = tid >> 8;                 // 0 -> row i0, 1 -> row i0+1
  int px = tid & 255;                  // output column
  float xs = px * (127.f / 255.f);
  float x0f = floorf(xs);
  int x0 = (int)x0f;
  float wx = xs - x0f, omwx = 1.f - wx;

  f32x4 acc[2][4];
#pragma unroll
  for (int mt = 0; mt < 2; ++mt)
#pragma unroll
    for (int xt = 0; xt < 4; ++xt)
      acc[mt][xt] = (f32x4){0.f, 0.f, 0.f, 0.f};

  int wv = tid >> 6;                   // wave 0..7
  int cg = (tid >> 4) & 3;             // lane's k-granule within the B-frag
  const size_t tbase = (size_t)n * CMID * (HL * WL);
  float* chMine = smem + half * 4096;  // own half's staged rows

#pragma unroll
  for (int cb = 0; cb < 4; ++cb) {
    __syncthreads();                   // B0: prev mfma reads of glb done
    // stage combined rows for BOTH halves: 2048 float4 items, 4 iters/thread,
    // hs compile-time per unrolled iter (f = tid + it*512 -> hs = it>>1).
#pragma unroll
    for (int it = 0; it < 4; ++it) {
      int f = tid + it * 512;
      const int hs = it >> 1;          // 0,0,1,1
      int rem = f & 1023;
      int cc = rem >> 5, x4 = (rem & 31) * 4;
      int yy0 = hs ? y0B : y0A, yy1 = hs ? y1B : y1A;
      float w1v = hs ? wyB : wyA, w0v = hs ? omwyB : omwyA;
      const float* base = t + tbase + (size_t)(cb * 32 + cc) * (HL * WL) + x4;
      float4 a = *(const float4*)(base + yy0 * WL);
      float4 b = *(const float4*)(base + yy1 * WL);
      float4 cmb;
      cmb.x = fmaf(a.x, w0v, b.x * w1v);
      cmb.y = fmaf(a.y, w0v, b.y * w1v);
      cmb.z = fmaf(a.z, w0v, b.z * w1v);
      cmb.w = fmaf(a.w, w0v, b.w * w1v);
      *(float4*)&smem[hs * 4096 + cc * 128 + x4] = cmb;
    }
    __syncthreads();                   // B1: staging ready

    unsigned gp[16];
#pragma unroll
    for (int pq = 0; pq < 16; ++pq) {
      const float* c0 = &chMine[(2 * pq) * 128 + x0];
      float g0 = gelu_fast(fmaf(c0[0], omwx, c0[1] * wx));
      const float* c1 = c0 + 128;
      float g1 = gelu_fast(fmaf(c1[0], omwx, c1[1] * wx));
      h2v hv;
      hv.x = (_Float16)g0;             // RNE casts for accuracy
      hv.y = (_Float16)g1;
      gp[pq] = __builtin_bit_cast(unsigned, hv);
    }
    __syncthreads();                   // B2: ALL staging reads done; reuse

    // write this pixel's 64B B-row IN PLACE (panel row = tid), XOR-swizzled
    int xsw = (tid & 3) ^ ((tid >> 2) & 3);
    char* grow = glb + tid * 64;
    uint4 q;
    q.x = gp[0];  q.y = gp[1];  q.z = gp[2];  q.w = gp[3];
    *(uint4*)(grow + ((0 ^ xsw) << 4)) = q;
    q.x = gp[4];  q.y = gp[5];  q.z = gp[6];  q.w = gp[7];
    *(uint4*)(grow + ((1 ^ xsw) << 4)) = q;
    q.x = gp[8];  q.y = gp[9];  q.z = gp[10]; q.w = gp[11];
    *(uint4*)(grow + ((2 ^ xsw) << 4)) = q;
    q.x = gp[12]; q.y = gp[13]; q.z = gp[14]; q.w = gp[15];
    *(uint4*)(grow + ((3 ^ xsw) << 4)) = q;
    __syncthreads();                   // B3: glb ready

#pragma unroll
    for (int xt = 0; xt < 4; ++xt) {
      int xrow = wv * 64 + xt * 16 + (tid & 15);
      int slot = cg ^ (xrow & 3) ^ ((xrow >> 2) & 3);
      h8v bfrag = *(const h8v*)(glb + xrow * 64 + (slot << 4));
      acc[0][xt] = __builtin_amdgcn_mfma_f32_16x16x32_f16(wfrag[cb * 2 + 0], bfrag,
                                                          acc[0][xt], 0, 0, 0);
      acc[1][xt] = __builtin_amdgcn_mfma_f32_16x16x32_f16(wfrag[cb * 2 + 1], bfrag,
                                                          acc[1][xt], 0, 0, 0);
    }
  }

  // D-phase: intra-wave transpose, two half-phases of 4 waves x 8KB slots
  // (stride 128B, XOR-8 swizzle). Wave wv's slot holds its 64 pixels.
  float accv[32];
#pragma unroll
  for (int phD = 0; phD < 2; ++phD) {
    __syncthreads();                   // region free
    if ((wv >> 2) == phD) {
      char* slotb = (char*)smem + (wv & 3) * 8192;
#pragma unroll
      for (int mt = 0; mt < 2; ++mt)
#pragma unroll
        for (int xt = 0; xt < 4; ++xt) {
          int lr = xt * 16 + (tid & 15);        // row within wave
          int go = mt * 4 + ((tid >> 4) & 3);   // o-chunk index (4 f32)
          *(f32x4*)(slotb + lr * 128 + ((go ^ (lr & 7)) << 4)) = acc[mt][xt];
        }
    }
    __syncthreads();                   // writes visible
    if ((wv >> 2) == phD) {
      char* slotb = (char*)smem + (wv & 3) * 8192;
      int lr = tid & 63;
#pragma unroll
      for (int gg = 0; gg < 8; ++gg) {
        f32x4 v = *(const f32x4*)(slotb + lr * 128 + ((gg ^ (lr & 7)) << 4));
        accv[4 * gg + 0] = v[0];
        accv[4 * gg + 1] = v[1];
        accv[4 * gg + 2] = v[2];
        accv[4 * gg + 3] = v[3];
      }
    }
  }
  __syncthreads();                     // all D reads done; lmaxS/lsumS may alias

#pragma unroll
  for (int o = 0; o < 32; ++o) accv[o] += bn[o];

  int i_my = i0 + half;
  // odd channels -> refodd
#pragma unroll
  for (int k = 0; k < 16; ++k)
    refodd[(((size_t)(n * 16 + k)) * HO + i_my) * WO + px] = accv[2 * k + 1];

  // even channels: per-row softmax + cumsum -> gy. Row reduction spans the
  // 4 waves of the same half; lmaxS/lsumS indexed [k][half][wave-in-row].
  int lane2 = tid & 63, wir = wv & 3;
#pragma unroll
  for (int k = 0; k < 16; ++k) {
    float m = accv[2 * k];
#pragma unroll
    for (int d = 32; d; d >>= 1) m = fmaxf(m, __shfl_xor(m, d, 64));
    if (lane2 == 0) lmaxS[k * 8 + half * 4 + wir] = m;
  }
  __syncthreads();
  float pk[16];
#pragma unroll
  for (int k = 0; k < 16; ++k) {
    const float* lm = &lmaxS[k * 8 + half * 4];
    float m = fmaxf(fmaxf(lm[0], lm[1]), fmaxf(lm[2], lm[3]));
    float pv = __expf(accv[2 * k] - m);
#pragma unroll
    for (int d = 1; d < 64; d <<= 1) {
      float q = __shfl_up(pv, d, 64);
      if (lane2 >= d) pv += q;
    }
    pk[k] = pv;
    if (lane2 == 63) lsumS[k * 8 + half * 4 + wir] = pv;
  }
  __syncthreads();
#pragma unroll
  for (int k = 0; k < 16; ++k) {
    const float* ls = &lsumS[k * 8 + half * 4];
    float off = 0.f, tot = 0.f;
#pragma unroll
    for (int q = 0; q < 4; ++q) {
      float x = ls[q];
      tot += x;
      if (q < wir) off += x;
    }
    gy[((size_t)(n * 16 + k) * HO + i_my) * WO + px] =
        (pk[k] + off) * (255.f * __builtin_amdgcn_rcpf(tot));
  }
}

// K5: column softmax+cumsum -> gx, in place over refodd.
__global__ __launch_bounds__(256) void k5_colscan(float* __restrict__ refodd) {
  int blk = blockIdx.x;           // nk*4 + cg
  int nk = blk >> 2, cg = blk & 3;
  int tid = threadIdx.x;
  int c = tid >> 6, j = tid & 63;
  __shared__ float lmax[4 * 64], lsum[4 * 64];
  float* img = refodd + (size_t)nk * (HO * WO) + cg * 64 + j;

  float p[64];
  float m = -1e30f;
#pragma unroll
  for (int q = 0; q < 64; ++q) {
    p[q] = img[(size_t)(c * 64 + q) * WO];
    m = fmaxf(m, p[q]);
  }
  lmax[c * 64 + j] = m;
  __syncthreads();
  m = fmaxf(fmaxf(lmax[j], lmax[64 + j]), fmaxf(lmax[128 + j], lmax[192 + j]));
  float s = 0.f;
#pragma unroll
  for (int q = 0; q < 64; ++q) {
    p[q] = __expf(p[q] - m);
    s += p[q];
  }
  lsum[c * 64 + j] = s;
  __syncthreads();
  float off = 0.f, tot = 0.f;
#pragma unroll
  for (int q2 = 0; q2 < 4; ++q2) {
    float x = lsum[q2 * 64 + j];
    tot += x;
    if (q2 < c) off += x;
  }
  float inv255 = 255.f * __builtin_amdgcn_rcpf(tot);
  float run = off;
#pragma unroll
  for (int q = 0; q < 64; ++q) {
    run += p[q];
    img[(size_t)(c * 64 + q) * WO] = run * inv255;
  }
}

// K6 v5: LANE = COLUMN remap (taps hit 1-3 lines per wave load) + XCD swizzle.
// Unchanged from round 11.
__global__ __launch_bounds__(256, 4) void k6_sample_t5(const float* __restrict__ gx,
                                                       const float* __restrict__ hi,
                                                       float* out) {
  int blk = (blockIdx.x & 7) * 512 + (blockIdx.x >> 3);  // bijective: 4096 = 8*512
  int nk = blk >> 4, ti = (blk >> 2) & 3, tj = blk & 3;
  __shared__ float gxl[64 * 65];   // coords; becomes result tile
  __shared__ float gyl[64 * 65];
  int tid = threadIdx.x;
  const size_t ibase = (size_t)nk * (HO * WO);
  const size_t tb = ibase + (size_t)(ti * 64) * WO + tj * 64;
  const float* himg = hi + ibase;

  // Phase 0: dense coalesced stage of gx and gy (gy aliases out).
#pragma unroll
  for (int ph = 0; ph < 4; ++ph) {
    int r = ph * 16 + (tid >> 4), c4 = (tid & 15) * 4;
    float4 vx = *(const float4*)(gx + tb + (size_t)r * WO + c4);
    float4 vy = *(const float4*)(out + tb + (size_t)r * WO + c4);
    int a = r * 65 + c4;
    gxl[a] = vx.x; gxl[a + 1] = vx.y; gxl[a + 2] = vx.z; gxl[a + 3] = vx.w;
    gyl[a] = vy.x; gyl[a + 1] = vy.y; gyl[a + 2] = vy.z; gyl[a + 3] = vy.w;
  }
  __syncthreads();

  // Phase 1: thread (col jl, rows ig*16..+15) reads its 32 coords from LDS
  // (lane-stride 1 -> conflict-free) and issues ALL 64 taps.
  int jl = tid & 63, ig = tid >> 6;
  const float* lgx = &gxl[jl];
  const float* lgy = &gyl[jl];
  float wxa[16], wya[16];
  float v00[16], v01[16], v10[16], v11[16];
#pragma unroll
  for (int s = 0; s < 16; ++s) {
    int r = ig * 16 + s;
    float xf = lgx[r * 65], yf = lgy[r * 65];
    float x0f = floorf(xf), y0f = floorf(yf);
    wxa[s] = xf - x0f; wya[s] = yf - y0f;
    int x0 = (int)x0f, y0 = (int)y0f;
    int x1 = min(x0 + 1, 255), y1 = min(y0 + 1, 255);
    const float* r0 = himg + y0 * WO;
    const float* r1 = himg + y1 * WO;
    v00[s] = r0[x0]; v01[s] = r0[x1];
    v10[s] = r1[x0]; v11[s] = r1[x1];
  }
  // Real compiler memory barrier: loads cannot sink past it.
  asm volatile("" ::: "memory");
  __syncthreads();

  // Phase 2: bilinear combine; results overwrite gxl (same slots just read).
  float* lres = &gxl[jl];
#pragma unroll
  for (int s = 0; s < 16; ++s) {
    int r = ig * 16 + s;
    float top = fmaf(v01[s] - v00[s], wxa[s], v00[s]);
    float bot = fmaf(v11[s] - v10[s], wxa[s], v10[s]);
    lres[r * 65] = fmaf(bot - top, wya[s], top);
  }
  __syncthreads();

  // Phase 3: dense store (wave covers 16 full 256B rows).
#pragma unroll
  for (int ph = 0; ph < 4; ++ph) {
    int r = ph * 16 + (tid >> 4), c4 = (tid & 15) * 4;
    int a = r * 65 + c4;
    float4 v;
    v.x = gxl[a]; v.y = gxl[a + 1]; v.z = gxl[a + 2]; v.w = gxl[a + 3];
    *(float4*)(out + tb + (size_t)r * WO + c4) = v;
  }
}

extern "C" void kernel_launch(void* const* d_in, const int* in_sizes, int n_in,
                              void* d_out, int out_size, void* d_ws, size_t ws_size,
                              hipStream_t stream) {
  (void)in_sizes; (void)n_in; (void)out_size; (void)ws_size;
  const float* lo  = (const float*)d_in[0];
  const float* hi  = (const float*)d_in[1];
  const float* w1  = (const float*)d_in[2];
  const float* b1  = (const float*)d_in[3];
  const float* gnw = (const float*)d_in[4];
  const float* gnb = (const float*)d_in[5];
  const float* sw1 = (const float*)d_in[6];
  const float* sw2 = (const float*)d_in[7];
  const float* w2  = (const float*)d_in[8];
  float* ws = (float*)d_ws;
  float* t       = ws;                    // 33,554,432 floats
  float* refodd  = ws + 33554432;         // 16,777,216 floats (becomes gx in place)
  float* S1p     = ws + 50331648;         // 8192
  float* S2p     = S1p + 8192;            // 8192
  unsigned short* wAf = (unsigned short*)(S2p + 8192);  // 65,536 f16 in old w2effT slot
  float* beff    = S2p + 8192 + 65536;    // 512
  float* w1T     = beff + 512;            // 8192
  float* out     = (float*)d_out;
  float* gybuf   = out;                   // gy aliases d_out

  k0_transpose<<<dim3(1), dim3(256), 0, stream>>>(w1, w1T);
  k1_conv1<<<dim3(2048), dim3(512), 0, stream>>>(lo, w1T, b1, t);
  k2_statsT<0><<<dim3(2048), dim3(256), 0, stream>>>(t, S1p, S2p);
  k2_statsT<1><<<dim3(2048), dim3(256), 0, stream>>>(t, S1p, S2p);
  k2_statsT<2><<<dim3(2048), dim3(256), 0, stream>>>(t, S1p, S2p);
  k2_statsT<3><<<dim3(2048), dim3(256), 0, stream>>>(t, S1p, S2p);
  k2b_prep<<<dim3(16), dim3(128), 0, stream>>>(S1p, S2p, gnw, gnb, sw1, sw2, w2, wAf, beff);
  k3_ref2<<<dim3(2048), dim3(512), 0, stream>>>(t, wAf, beff, refodd, gybuf);
  k5_colscan<<<dim3(1024), dim3(256), 0, stream>>>(refodd);
  k6_sample_t5<<<dim3(4096), dim3(256), 0, stream>>>(refodd, hi, out);
}

// Round 13
// 593.928 us; speedup vs baseline: 1.2716x; 1.2716x over previous
//
#include <hip/hip_runtime.h>
#include <math.h>

#define N_IMG 16
#define CIN   64
#define CMID  128
#define CO    32
#define KHD   16
#define HL    128
#define WL    128
#define HO    256
#define WO    256
#define EPSV  1e-5f

typedef float f32x4 __attribute__((ext_vector_type(4)));
typedef _Float16 h8v __attribute__((ext_vector_type(8)));
typedef _Float16 h2v __attribute__((ext_vector_type(2)));

// ---------------- workspace layout (floats) ----------------
// [0, 33554432)            t (16,128,128,128)       -- dead after K3
// [33554432, 50331648)     refodd (16,16,256,256)   -- K5 overwrites in place with gx
// [50331648, +8192)        S1p (4,2048)
// [+8192, +8192)           S2p (4,2048)
// [+..., 65536 f32 slot)   wAf: f16 A-fragments (16 n x 4 cb x 2 mt x 64 lane x 8)
// [+..., 512)              beff (16,32)
// [+..., 8192)             w1T (64,128)  [c][o]
// gy lives in d_out (K6 stages its gy tile into LDS before overwriting).

// K0: transpose conv1 weights to [c][o] so K1 can read them wave-uniformly.
__global__ __launch_bounds__(256) void k0_transpose(const float* __restrict__ w1,
                                                    float* __restrict__ w1T) {
  int tid = threadIdx.x;
  for (int f = tid; f < CMID * CIN; f += 256) {
    int o = f >> 6, c = f & 63;
    w1T[c * CMID + o] = w1[f];
  }
}

// K1: t[n][o][y][x] = conv1_b[o] + sum_c conv1_w[o][c] * lo[n][c][y][x]
__global__ __launch_bounds__(512) void k1_conv1(const float* __restrict__ lo,
                                                const float* __restrict__ w1T,
                                                const float* __restrict__ b1,
                                                float* __restrict__ t) {
  int blk = blockIdx.x;        // n*128 + y
  int n = blk >> 7, y = blk & 127;
  __shared__ float lo_l[CIN * WL];    // [c][x]  32 KB
  int tid = threadIdx.x;
  const float* lo_base = lo + (size_t)n * CIN * (HL * WL) + y * WL;
  for (int f = tid; f < CIN * WL / 4; f += 512) {
    int c = f >> 5, xi = f & 31;
    ((float4*)lo_l)[f] = *(const float4*)(lo_base + (size_t)c * (HL * WL) + xi * 4);
  }
  __syncthreads();

  int wave = __builtin_amdgcn_readfirstlane(tid >> 6);  // force wave-uniform
  int lane = tid & 63;
  int half = wave >> 2;   // x-half
  int og   = wave & 3;    // 32-output group
  int x = half * 64 + lane;

  float acc[32];
#pragma unroll
  for (int o = 0; o < 32; ++o) acc[o] = 0.f;

  const float* wbase = w1T + og * 32;   // [c][o], stride CMID; uniform
  for (int c = 0; c < CIN; ++c) {
    float lv = lo_l[c * WL + x];
    const float* wr = wbase + c * CMID;
#pragma unroll
    for (int o = 0; o < 32; ++o) acc[o] += wr[o] * lv;
  }
  const float* bb = b1 + og * 32;       // uniform
  float* tb = t + ((size_t)n * CMID + og * 32) * (HL * WL) + y * WL + x;
#pragma unroll
  for (int o = 0; o < 32; ++o) tb[(size_t)o * (HL * WL)] = acc[o] + bb[o];
}

// Fast erf (A&S 7.1.26, |err| <= 1.5e-7), DIV-FREE: v_rcp instead of IEEE divide.
__device__ __forceinline__ float erf_fast(float x) {
  float ax = fabsf(x);
  float t = __builtin_amdgcn_rcpf(fmaf(0.3275911f, ax, 1.f));
  float e = __expf(-ax * ax);
  float poly = t * (0.254829592f +
              t * (-0.284496736f +
              t * (1.421413741f +
              t * (-1.453152027f +
              t * 1.061405429f))));
  float r = fmaf(-poly, e, 1.f);
  return copysignf(r, x);
}

__device__ __forceinline__ float gelu_fast(float v) {
  float h = 0.5f * v;
  return fmaf(h, erf_fast(v * 0.70710678118654752f), h);
}

// K2 (templated on Q): per (n,c): partial sum & sumsq of GELU(upsample(t[n,c]))
// over output rows [Q*64, Q*64+64). Entire y-schedule compile-time; rolling
// register pair of x-interped rows. (unchanged from round 10)
template <int Q>
__global__ __launch_bounds__(256) void k2_statsT(const float* __restrict__ t,
                                                 float* __restrict__ S1p,
                                                 float* __restrict__ S2p) {
  constexpr int I0  = Q * 64;
  constexpr int YLO = (I0 * 127) / 255;
  constexpr int YHI0 = ((I0 + 63) * 127) / 255 + 1;
  constexpr int YHI = (YHI0 > 127) ? 127 : YHI0;
  constexpr int NR  = YHI - YLO + 1;            // 33 or 34
  int nc = blockIdx.x;                          // 2048 blocks
  __shared__ float img[NR * WL];
  __shared__ float red[16];
  int tid = threadIdx.x;
  const float* tb = t + (size_t)nc * (HL * WL) + YLO * WL;
  for (int f = tid; f < NR * (WL / 4); f += 256)
    ((float4*)img)[f] = ((const float4*)tb)[f];
  __syncthreads();

  float xs = tid * (127.f / 255.f);
  float x0f = floorf(xs);
  int x0 = (int)x0f, x1 = min(x0 + 1, 127);
  float wx = xs - x0f, omwx = 1.f - wx;

  auto xv = [&](int r) {
    return img[r * WL + x0] * omwx + img[r * WL + x1] * wx;
  };

  float sum = 0.f, ssq = 0.f;
  float cur0 = xv(0);                  // row y0(I0) == YLO
  float cur1 = xv(1);                  // NR >= 2 always
#pragma unroll
  for (int k = 0; k < 64; ++k) {
    const int i = I0 + k;
    const int y0k = (i * 127) / 255;                 // compile-time
    if (k > 0 && y0k != ((i - 1) * 127) / 255) {     // static advance
      cur0 = cur1;
      if (y0k + 1 <= YHI) cur1 = xv(y0k + 1 - YLO);
    }
    const float wyk = (float)(i * 127 - 255 * y0k) * (1.f / 255.f);  // exact
    float v = (y0k + 1 <= YHI) ? fmaf(cur0, 1.f - wyk, cur1 * wyk)
                               : cur0;               // i==255: wy==0
    float g = gelu_fast(v);
    sum += g; ssq += g * g;
  }
  int lane = tid & 63, w = tid >> 6;
#pragma unroll
  for (int d = 32; d; d >>= 1) {
    sum += __shfl_xor(sum, d, 64);
    ssq += __shfl_xor(ssq, d, 64);
  }
  if (lane == 0) { red[w] = sum; red[8 + w] = ssq; }
  __syncthreads();
  if (tid == 0) {
    S1p[Q * 2048 + nc] = red[0] + red[1] + red[2] + red[3];
    S2p[Q * 2048 + nc] = red[8] + red[9] + red[10] + red[11];
  }
}

// K2b: fold GN + SE + conv2 into per-image effective weights + bias.
// Weights are emitted as f16 MFMA A-fragments for v_mfma_f32_16x16x32_f16:
//   A[row=o&15][k=c&31] of tile (cb=c>>5, mt=o>>4); lane = ((c&31)>>3)*16 + (o&15),
//   element j = c&7  ->  wAf[((n*4+cb)*2+mt)*512 + lane*8 + j]
__global__ __launch_bounds__(128) void k2b_prep(const float* __restrict__ S1p,
                                                const float* __restrict__ S2p,
                                                const float* __restrict__ gn_w,
                                                const float* __restrict__ gn_b,
                                                const float* __restrict__ se_w1,
                                                const float* __restrict__ se_w2,
                                                const float* __restrict__ w2,
                                                unsigned short* __restrict__ wAf,
                                                float* __restrict__ beff) {
  int n = blockIdx.x, c = threadIdx.x;
  int nc = n * 128 + c;
  __shared__ float mArr[128], eArr[128], pArr[128], hArr[16], dArr[128];
  const float inv = 1.f / 65536.f;
  float m  = (S1p[nc] + S1p[2048 + nc] + S1p[4096 + nc] + S1p[6144 + nc]) * inv;
  float e2 = (S2p[nc] + S2p[2048 + nc] + S2p[4096 + nc] + S2p[6144 + nc]) * inv;
  mArr[c] = m; eArr[c] = e2;
  __syncthreads();
  int g0 = (c >> 6) << 6;
  float mu = 0.f, E2 = 0.f;
  for (int q = 0; q < 64; ++q) { mu += mArr[g0 + q]; E2 += eArr[g0 + q]; }
  mu *= (1.f / 64.f); E2 *= (1.f / 64.f);
  float var = E2 - mu * mu;
  float rs = rsqrtf(var + EPSV);
  float gw = gn_w[c], gb = gn_b[c];
  pArr[c] = (m - mu) * rs * gw + gb;
  __syncthreads();
  if (c < 16) {
    float h = 0.f;
    for (int q = 0; q < 128; ++q) h += se_w1[c * 128 + q] * pArr[q];
    hArr[c] = fmaxf(h, 0.f);
  }
  __syncthreads();
  float sacc = 0.f;
  for (int q = 0; q < 16; ++q) sacc += se_w2[c * 16 + q] * hArr[q];
  float s = __builtin_amdgcn_rcpf(1.f + __expf(-sacc));
  float a = s * gw * rs;
  float d = s * (gb - gw * rs * mu);
  dArr[c] = d;
  __syncthreads();
  int cb = c >> 5;
  int lbase = ((c >> 3) & 3) << 4;   // (lane>>4) = (c&31)>>3
  int j = c & 7;
#pragma unroll
  for (int o = 0; o < 32; ++o) {
    int mt = o >> 4;
    size_t idx = ((size_t)n * 8 + (size_t)(cb * 2 + mt)) * 512 +
                 (size_t)((lbase + (o & 15)) * 8 + j);
    _Float16 hv = (_Float16)(w2[o * 128 + c] * a);
    wAf[idx] = __builtin_bit_cast(unsigned short, hv);
  }
  if (c < 32) {
    float bb = 0.f;
    for (int q = 0; q < 128; ++q) bb += w2[c * 128 + q] * dArr[q];
    beff[n * 32 + c] = bb;
  }
}

// K3 v2b: TWO output rows per block (512 threads, grid 2048), launch bounds
// RELAXED to (512, 4). Round 12's (512, 8) capped VGPR at 64 and the allocator
// spilled acc/accv to scratch: VGPR_Count=32, FETCH 365 MB, WRITE 701 MB
// (~668 B/thread of spill round-trips), 326us. The 2-row structure itself
// (shared staging, barriers per row halved) was never tested -- this round
// tests it spill-free. LDS 32.8 KB -> 4 blocks/CU; VGPR free to settle ~60-100.
__global__ __launch_bounds__(512, 4) void k3_ref2(const float* __restrict__ t,
                                                  const unsigned short* __restrict__ wAf,
                                                  const float* __restrict__ beff,
                                                  float* __restrict__ refodd,
                                                  float* __restrict__ gy) {
  int blk = (blockIdx.x & 7) * 256 + (blockIdx.x >> 3);  // bijective: 2048 = 8*256
  int n = blk >> 7, p2 = blk & 127;
  int i0 = 2 * p2;                     // rows i0, i0+1
  __shared__ float smem[8196];         // 32,784 B: 8192 shared + 4 guard
  int tid = threadIdx.x;
  char* glb = (char*)smem;             // f16 B-panel view (512 rows x 64B)
  float* lmaxS = smem;                 // epilogue alias (behind barrier)
  float* lsumS = smem + 128;
  const float* bn = beff + n * CO;     // uniform

  if (tid < 4) smem[8192 + tid] = 0.f; // guard: finite for the x0+1 read at
                                       // cc=31,px=255 of half 1; half 0's
                                       // equivalent read lands in half 1's
                                       // staged data (finite, x-weight 0)

  int lane = tid & 63;
  h8v wfrag[8];                        // A-frags: [cb][mt], resident all kernel
#pragma unroll
  for (int u = 0; u < 8; ++u)
    wfrag[u] = *(const h8v*)(wAf + ((size_t)n * 8 + u) * 512 + lane * 8);

  // y-params for BOTH rows (used by staging); own-row params for gelu phase.
  float ysA = i0 * (127.f / 255.f);
  float y0fA = floorf(ysA);
  int y0A = (int)y0fA, y1A = min(y0A + 1, 127);
  float wyA = ysA - y0fA, omwyA = 1.f - wyA;
  float ysB = (i0 + 1) * (127.f / 255.f);
  float y0fB = floorf(ysB);
  int y0B = (int)y0fB, y1B = min(y0B + 1, 127);
  float wyB = ysB - y0fB, omwyB = 1.f - wyB;

  int half = tid >> 8;                 // 0 -> row i0, 1 -> row i0+1
  int px = tid & 255;                  // output column
  float xs = px * (127.f / 255.f);
  float x0f = floorf(xs);
  int x0 = (int)x0f;
  float wx = xs - x0f, omwx = 1.f - wx;

  f32x4 acc[2][4];
#pragma unroll
  for (int mt = 0; mt < 2; ++mt)
#pragma unroll
    for (int xt = 0; xt < 4; ++xt)
      acc[mt][xt] = (f32x4){0.f, 0.f, 0.f, 0.f};

  int wv = tid >> 6;                   // wave 0..7
  int cg = (tid >> 4) & 3;             // lane's k-granule within the B-frag
  const size_t tbase = (size_t)n * CMID * (HL * WL);
  float* chMine = smem + half * 4096;  // own half's staged rows

#pragma unroll
  for (int cb = 0; cb < 4; ++cb) {
    __syncthreads();                   // B0: prev mfma reads of glb done
    // stage combined rows for BOTH halves: 2048 float4 items, 4 iters/thread,
    // hs compile-time per unrolled iter (f = tid + it*512 -> hs = it>>1).
#pragma unroll
    for (int it = 0; it < 4; ++it) {
      int f = tid + it * 512;
      const int hs = it >> 1;          // 0,0,1,1
      int rem = f & 1023;
      int cc = rem >> 5, x4 = (rem & 31) * 4;
      int yy0 = hs ? y0B : y0A, yy1 = hs ? y1B : y1A;
      float w1v = hs ? wyB : wyA, w0v = hs ? omwyB : omwyA;
      const float* base = t + tbase + (size_t)(cb * 32 + cc) * (HL * WL) + x4;
      float4 a = *(const float4*)(base + yy0 * WL);
      float4 b = *(const float4*)(base + yy1 * WL);
      float4 cmb;
      cmb.x = fmaf(a.x, w0v, b.x * w1v);
      cmb.y = fmaf(a.y, w0v, b.y * w1v);
      cmb.z = fmaf(a.z, w0v, b.z * w1v);
      cmb.w = fmaf(a.w, w0v, b.w * w1v);
      *(float4*)&smem[hs * 4096 + cc * 128 + x4] = cmb;
    }
    __syncthreads();                   // B1: staging ready

    unsigned gp[16];
#pragma unroll
    for (int pq = 0; pq < 16; ++pq) {
      const float* c0 = &chMine[(2 * pq) * 128 + x0];
      float g0 = gelu_fast(fmaf(c0[0], omwx, c0[1] * wx));
      const float* c1 = c0 + 128;
      float g1 = gelu_fast(fmaf(c1[0], omwx, c1[1] * wx));
      h2v hv;
      hv.x = (_Float16)g0;             // RNE casts for accuracy
      hv.y = (_Float16)g1;
      gp[pq] = __builtin_bit_cast(unsigned, hv);
    }
    __syncthreads();                   // B2: ALL staging reads done; reuse

    // write this pixel's 64B B-row IN PLACE (panel row = tid), XOR-swizzled
    int xsw = (tid & 3) ^ ((tid >> 2) & 3);
    char* grow = glb + tid * 64;
    uint4 q;
    q.x = gp[0];  q.y = gp[1];  q.z = gp[2];  q.w = gp[3];
    *(uint4*)(grow + ((0 ^ xsw) << 4)) = q;
    q.x = gp[4];  q.y = gp[5];  q.z = gp[6];  q.w = gp[7];
    *(uint4*)(grow + ((1 ^ xsw) << 4)) = q;
    q.x = gp[8];  q.y = gp[9];  q.z = gp[10]; q.w = gp[11];
    *(uint4*)(grow + ((2 ^ xsw) << 4)) = q;
    q.x = gp[12]; q.y = gp[13]; q.z = gp[14]; q.w = gp[15];
    *(uint4*)(grow + ((3 ^ xsw) << 4)) = q;
    __syncthreads();                   // B3: glb ready

#pragma unroll
    for (int xt = 0; xt < 4; ++xt) {
      int xrow = wv * 64 + xt * 16 + (tid & 15);
      int slot = cg ^ (xrow & 3) ^ ((xrow >> 2) & 3);
      h8v bfrag = *(const h8v*)(glb + xrow * 64 + (slot << 4));
      acc[0][xt] = __builtin_amdgcn_mfma_f32_16x16x32_f16(wfrag[cb * 2 + 0], bfrag,
                                                          acc[0][xt], 0, 0, 0);
      acc[1][xt] = __builtin_amdgcn_mfma_f32_16x16x32_f16(wfrag[cb * 2 + 1], bfrag,
                                                          acc[1][xt], 0, 0, 0);
    }
  }

  // D-phase: intra-wave transpose, two half-phases of 4 waves x 8KB slots
  // (stride 128B, XOR-8 swizzle). Wave wv's slot holds its 64 pixels.
  float accv[32];
#pragma unroll
  for (int phD = 0; phD < 2; ++phD) {
    __syncthreads();                   // region free
    if ((wv >> 2) == phD) {
      char* slotb = (char*)smem + (wv & 3) * 8192;
#pragma unroll
      for (int mt = 0; mt < 2; ++mt)
#pragma unroll
        for (int xt = 0; xt < 4; ++xt) {
          int lr = xt * 16 + (tid & 15);        // row within wave
          int go = mt * 4 + ((tid >> 4) & 3);   // o-chunk index (4 f32)
          *(f32x4*)(slotb + lr * 128 + ((go ^ (lr & 7)) << 4)) = acc[mt][xt];
        }
    }
    __syncthreads();                   // writes visible
    if ((wv >> 2) == phD) {
      char* slotb = (char*)smem + (wv & 3) * 8192;
      int lr = tid & 63;
#pragma unroll
      for (int gg = 0; gg < 8; ++gg) {
        f32x4 v = *(const f32x4*)(slotb + lr * 128 + ((gg ^ (lr & 7)) << 4));
        accv[4 * gg + 0] = v[0];
        accv[4 * gg + 1] = v[1];
        accv[4 * gg + 2] = v[2];
        accv[4 * gg + 3] = v[3];
      }
    }
  }
  __syncthreads();                     // all D reads done; lmaxS/lsumS may alias

#pragma unroll
  for (int o = 0; o < 32; ++o) accv[o] += bn[o];

  int i_my = i0 + half;
  // odd channels -> refodd
#pragma unroll
  for (int k = 0; k < 16; ++k)
    refodd[(((size_t)(n * 16 + k)) * HO + i_my) * WO + px] = accv[2 * k + 1];

  // even channels: per-row softmax + cumsum -> gy. Row reduction spans the
  // 4 waves of the same half; lmaxS/lsumS indexed [k][half][wave-in-row].
  int lane2 = tid & 63, wir = wv & 3;
#pragma unroll
  for (int k = 0; k < 16; ++k) {
    float m = accv[2 * k];
#pragma unroll
    for (int d = 32; d; d >>= 1) m = fmaxf(m, __shfl_xor(m, d, 64));
    if (lane2 == 0) lmaxS[k * 8 + half * 4 + wir] = m;
  }
  __syncthreads();
  float pk[16];
#pragma unroll
  for (int k = 0; k < 16; ++k) {
    const float* lm = &lmaxS[k * 8 + half * 4];
    float m = fmaxf(fmaxf(lm[0], lm[1]), fmaxf(lm[2], lm[3]));
    float pv = __expf(accv[2 * k] - m);
#pragma unroll
    for (int d = 1; d < 64; d <<= 1) {
      float q = __shfl_up(pv, d, 64);
      if (lane2 >= d) pv += q;
    }
    pk[k] = pv;
    if (lane2 == 63) lsumS[k * 8 + half * 4 + wir] = pv;
  }
  __syncthreads();
#pragma unroll
  for (int k = 0; k < 16; ++k) {
    const float* ls = &lsumS[k * 8 + half * 4];
    float off = 0.f, tot = 0.f;
#pragma unroll
    for (int q = 0; q < 4; ++q) {
      float x = ls[q];
      tot += x;
      if (q < wir) off += x;
    }
    gy[((size_t)(n * 16 + k) * HO + i_my) * WO + px] =
        (pk[k] + off) * (255.f * __builtin_amdgcn_rcpf(tot));
  }
}

// K5: column softmax+cumsum -> gx, in place over refodd.
__global__ __launch_bounds__(256) void k5_colscan(float* __restrict__ refodd) {
  int blk = blockIdx.x;           // nk*4 + cg
  int nk = blk >> 2, cg = blk & 3;
  int tid = threadIdx.x;
  int c = tid >> 6, j = tid & 63;
  __shared__ float lmax[4 * 64], lsum[4 * 64];
  float* img = refodd + (size_t)nk * (HO * WO) + cg * 64 + j;

  float p[64];
  float m = -1e30f;
#pragma unroll
  for (int q = 0; q < 64; ++q) {
    p[q] = img[(size_t)(c * 64 + q) * WO];
    m = fmaxf(m, p[q]);
  }
  lmax[c * 64 + j] = m;
  __syncthreads();
  m = fmaxf(fmaxf(lmax[j], lmax[64 + j]), fmaxf(lmax[128 + j], lmax[192 + j]));
  float s = 0.f;
#pragma unroll
  for (int q = 0; q < 64; ++q) {
    p[q] = __expf(p[q] - m);
    s += p[q];
  }
  lsum[c * 64 + j] = s;
  __syncthreads();
  float off = 0.f, tot = 0.f;
#pragma unroll
  for (int q2 = 0; q2 < 4; ++q2) {
    float x = lsum[q2 * 64 + j];
    tot += x;
    if (q2 < c) off += x;
  }
  float inv255 = 255.f * __builtin_amdgcn_rcpf(tot);
  float run = off;
#pragma unroll
  for (int q = 0; q < 64; ++q) {
    run += p[q];
    img[(size_t)(c * 64 + q) * WO] = run * inv255;
  }
}

// K6 v5: LANE = COLUMN remap (taps hit 1-3 lines per wave load) + XCD swizzle.
// Unchanged from round 11.
__global__ __launch_bounds__(256, 4) void k6_sample_t5(const float* __restrict__ gx,
                                                       const float* __restrict__ hi,
                                                       float* out) {
  int blk = (blockIdx.x & 7) * 512 + (blockIdx.x >> 3);  // bijective: 4096 = 8*512
  int nk = blk >> 4, ti = (blk >> 2) & 3, tj = blk & 3;
  __shared__ float gxl[64 * 65];   // coords; becomes result tile
  __shared__ float gyl[64 * 65];
  int tid = threadIdx.x;
  const size_t ibase = (size_t)nk * (HO * WO);
  const size_t tb = ibase + (size_t)(ti * 64) * WO + tj * 64;
  const float* himg = hi + ibase;

  // Phase 0: dense coalesced stage of gx and gy (gy aliases out).
#pragma unroll
  for (int ph = 0; ph < 4; ++ph) {
    int r = ph * 16 + (tid >> 4), c4 = (tid & 15) * 4;
    float4 vx = *(const float4*)(gx + tb + (size_t)r * WO + c4);
    float4 vy = *(const float4*)(out + tb + (size_t)r * WO + c4);
    int a = r * 65 + c4;
    gxl[a] = vx.x; gxl[a + 1] = vx.y; gxl[a + 2] = vx.z; gxl[a + 3] = vx.w;
    gyl[a] = vy.x; gyl[a + 1] = vy.y; gyl[a + 2] = vy.z; gyl[a + 3] = vy.w;
  }
  __syncthreads();

  // Phase 1: thread (col jl, rows ig*16..+15) reads its 32 coords from LDS
  // (lane-stride 1 -> conflict-free) and issues ALL 64 taps.
  int jl = tid & 63, ig = tid >> 6;
  const float* lgx = &gxl[jl];
  const float* lgy = &gyl[jl];
  float wxa[16], wya[16];
  float v00[16], v01[16], v10[16], v11[16];
#pragma unroll
  for (int s = 0; s < 16; ++s) {
    int r = ig * 16 + s;
    float xf = lgx[r * 65], yf = lgy[r * 65];
    float x0f = floorf(xf), y0f = floorf(yf);
    wxa[s] = xf - x0f; wya[s] = yf - y0f;
    int x0 = (int)x0f, y0 = (int)y0f;
    int x1 = min(x0 + 1, 255), y1 = min(y0 + 1, 255);
    const float* r0 = himg + y0 * WO;
    const float* r1 = himg + y1 * WO;
    v00[s] = r0[x0]; v01[s] = r0[x1];
    v10[s] = r1[x0]; v11[s] = r1[x1];
  }
  // Real compiler memory barrier: loads cannot sink past it.
  asm volatile("" ::: "memory");
  __syncthreads();

  // Phase 2: bilinear combine; results overwrite gxl (same slots just read).
  float* lres = &gxl[jl];
#pragma unroll
  for (int s = 0; s < 16; ++s) {
    int r = ig * 16 + s;
    float top = fmaf(v01[s] - v00[s], wxa[s], v00[s]);
    float bot = fmaf(v11[s] - v10[s], wxa[s], v10[s]);
    lres[r * 65] = fmaf(bot - top, wya[s], top);
  }
  __syncthreads();

  // Phase 3: dense store (wave covers 16 full 256B rows).
#pragma unroll
  for (int ph = 0; ph < 4; ++ph) {
    int r = ph * 16 + (tid >> 4), c4 = (tid & 15) * 4;
    int a = r * 65 + c4;
    float4 v;
    v.x = gxl[a]; v.y = gxl[a + 1]; v.z = gxl[a + 2]; v.w = gxl[a + 3];
    *(float4*)(out + tb + (size_t)r * WO + c4) = v;
  }
}

extern "C" void kernel_launch(void* const* d_in, const int* in_sizes, int n_in,
                              void* d_out, int out_size, void* d_ws, size_t ws_size,
                              hipStream_t stream) {
  (void)in_sizes; (void)n_in; (void)out_size; (void)ws_size;
  const float* lo  = (const float*)d_in[0];
  const float* hi  = (const float*)d_in[1];
  const float* w1  = (const float*)d_in[2];
  const float* b1  = (const float*)d_in[3];
  const float* gnw = (const float*)d_in[4];
  const float* gnb = (const float*)d_in[5];
  const float* sw1 = (const float*)d_in[6];
  const float* sw2 = (const float*)d_in[7];
  const float* w2  = (const float*)d_in[8];
  float* ws = (float*)d_ws;
  float* t       = ws;                    // 33,554,432 floats
  float* refodd  = ws + 33554432;         // 16,777,216 floats (becomes gx in place)
  float* S1p     = ws + 50331648;         // 8192
  float* S2p     = S1p + 8192;            // 8192
  unsigned short* wAf = (unsigned short*)(S2p + 8192);  // 65,536 f16 in old w2effT slot
  float* beff    = S2p + 8192 + 65536;    // 512
  float* w1T     = beff + 512;            // 8192
  float* out     = (float*)d_out;
  float* gybuf   = out;                   // gy aliases d_out

  k0_transpose<<<dim3(1), dim3(256), 0, stream>>>(w1, w1T);
  k1_conv1<<<dim3(2048), dim3(512), 0, stream>>>(lo, w1T, b1, t);
  k2_statsT<0><<<dim3(2048), dim3(256), 0, stream>>>(t, S1p, S2p);
  k2_statsT<1><<<dim3(2048), dim3(256), 0, stream>>>(t, S1p, S2p);
  k2_statsT<2><<<dim3(2048), dim3(256), 0, stream>>>(t, S1p, S2p);
  k2_statsT<3><<<dim3(2048), dim3(256), 0, stream>>>(t, S1p, S2p);
  k2b_prep<<<dim3(16), dim3(128), 0, stream>>>(S1p, S2p, gnw, gnb, sw1, sw2, w2, wAf, beff);
  k3_ref2<<<dim3(2048), dim3(512), 0, stream>>>(t, wAf, beff, refodd, gybuf);
  k5_colscan<<<dim3(1024), dim3(256), 0, stream>>>(refodd);
  k6_sample_t5<<<dim3(4096), dim3(256), 0, stream>>>(refodd, hi, out);
}